// Round 3
// baseline (2979.349 us; speedup 1.0000x reference)
//
#include <hip/hip_runtime.h>

#define N_ROWS 100000
#define NNODES 150000
#define D 32
#define NEDGE 5000000
#define BINSHIFT 7
#define BINSZ 128                     // nodes per bin
#define NBINS 1172                    // ceil(150000 / 128)
#define B1_BLOCKS 1024
#define B3_BLOCKS 512

// ---------------- binning (coarse counting sort by dst>>7) ----------------

__global__ void zero_bins(int* __restrict__ binCnt) {
    int i = blockIdx.x * blockDim.x + threadIdx.x;
    if (i < NBINS) binCnt[i] = 0;
}

__global__ void bin_hist(const int* __restrict__ dst, int* __restrict__ binCnt) {
    __shared__ int h[NBINS];
    for (int b = threadIdx.x; b < NBINS; b += blockDim.x) h[b] = 0;
    __syncthreads();
    int i = blockIdx.x * blockDim.x + threadIdx.x;
    const int stride = gridDim.x * blockDim.x;
    for (; i < NEDGE; i += stride) atomicAdd(&h[dst[i] >> BINSHIFT], 1);
    __syncthreads();
    for (int b = threadIdx.x; b < NBINS; b += blockDim.x) {
        int c = h[b];
        if (c) atomicAdd(&binCnt[b], c);  // lane-consecutive addresses: coalesced atomics
    }
}

__global__ void bin_scan(const int* __restrict__ binCnt, int* __restrict__ binPtr,
                         int* __restrict__ binCursor) {
    __shared__ int s[256];
    __shared__ int carry;
    const int t = threadIdx.x;
    if (t == 0) carry = 0;
    __syncthreads();
    for (int c = 0; c < (NBINS + 255) / 256; ++c) {
        int idx = c * 256 + t;
        int v = (idx < NBINS) ? binCnt[idx] : 0;
        s[t] = v;
        __syncthreads();
        for (int off = 1; off < 256; off <<= 1) {
            int tmp = (t >= off) ? s[t - off] : 0;
            __syncthreads();
            s[t] += tmp;
            __syncthreads();
        }
        int excl = carry + ((t == 0) ? 0 : s[t - 1]);
        if (idx < NBINS) { binPtr[idx] = excl; binCursor[idx] = excl; }
        __syncthreads();
        if (t == 0) carry += s[255];
        __syncthreads();
    }
    if (t == 0) binPtr[NBINS] = NEDGE;
}

// packed word: (dst & 127) << 18 | src   (src < 150000 < 2^18)
__global__ void bin_scatter(const int* __restrict__ src, const int* __restrict__ dst,
                            int* __restrict__ binCursor, unsigned int* __restrict__ binned) {
    __shared__ int h[NBINS];
    __shared__ int base[NBINS];
    const int t = threadIdx.x;
    for (int b = t; b < NBINS; b += 256) h[b] = 0;
    __syncthreads();
    const int chunk = (NEDGE + B3_BLOCKS - 1) / B3_BLOCKS;
    const int e0 = blockIdx.x * chunk;
    const int e1 = min(e0 + chunk, NEDGE);
    for (int i = e0 + t; i < e1; i += 256) atomicAdd(&h[dst[i] >> BINSHIFT], 1);
    __syncthreads();
    for (int b = t; b < NBINS; b += 256) {
        int c = h[b];
        base[b] = c ? atomicAdd(&binCursor[b], c) : 0;  // one reservation per (block,bin)
        h[b] = 0;
    }
    __syncthreads();
    for (int i = e0 + t; i < e1; i += 256) {
        int dv = dst[i];
        int bn = dv >> BINSHIFT;
        int r = atomicAdd(&h[bn], 1);  // LDS rank
        binned[base[bn] + r] = ((unsigned)(dv & (BINSZ - 1)) << 18) | (unsigned)src[i];
    }
}

// ---------------- per-layer compute ----------------

// h[i][j] = sum_k act(x[i][k]) * W[j][k] + b[j]
template <int MODE>
__global__ void linear_kernel(const float* __restrict__ xa, const float* __restrict__ xb,
                              const float* __restrict__ W, const float* __restrict__ b,
                              float* __restrict__ H) {
    __shared__ float Wt[D * D];
    __shared__ float bs[D];
    const int tid = threadIdx.x;
    for (int t = tid; t < D * D; t += blockDim.x) {
        int j = t / D, k = t % D;
        Wt[k * D + j] = W[j * D + k];
    }
    if (tid < D) bs[tid] = b[tid];
    __syncthreads();

    const int row = blockIdx.x * (blockDim.x / D) + tid / D;
    const int j = tid % D;
    if (row >= NNODES) return;

    float xv;
    if (MODE == 0) {
        xv = (row < N_ROWS) ? xa[row * D + j] : xb[(row - N_ROWS) * D + j];
    } else {
        xv = fmaxf(xa[row * D + j], 0.0f);
    }

    float acc = bs[j];
#pragma unroll
    for (int k = 0; k < D; ++k) {
        float a = __shfl(xv, k, D);
        acc = fmaf(a, Wt[k * D + j], acc);
    }
    H[row * D + j] = acc;
}

// One block per bin: 128x32 f32 accumulator in LDS, edge-parallel LDS atomics.
template <bool RELU>
__global__ void agg_lds(const int* __restrict__ binPtr, const unsigned int* __restrict__ binned,
                        const float* __restrict__ H, float* __restrict__ OUT) {
    __shared__ float acc[BINSZ * D];  // 16 KB
    const int t = threadIdx.x;
    const int bin = blockIdx.x;
    const int nodeBase = bin << BINSHIFT;
    const int nNodes = min(BINSZ, NNODES - nodeBase);
    for (int i = t; i < BINSZ * D; i += 256) acc[i] = 0.0f;
    __syncthreads();

    const int j = t & 31;
    const int g = t >> 5;  // 8 edge-groups per block
    const int e0 = binPtr[bin];
    const int e1 = binPtr[bin + 1];

    int e = e0 + g * 2;
    for (; e + 1 < e1; e += 16) {
        unsigned u0 = binned[e];
        unsigned u1 = binned[e + 1];
        float v0 = H[(u0 & 0x3FFFFu) * D + j];
        float v1 = H[(u1 & 0x3FFFFu) * D + j];
        atomicAdd(&acc[(u0 >> 18) * D + j], v0);
        atomicAdd(&acc[(u1 >> 18) * D + j], v1);
    }
    if (e < e1) {
        unsigned u = binned[e];
        float v = H[(u & 0x3FFFFu) * D + j];
        atomicAdd(&acc[(u >> 18) * D + j], v);
    }
    __syncthreads();

    for (int r = g; r < nNodes; r += 8) {
        const int node = nodeBase + r;
        float o = acc[r * D + j] + H[node * D + j];  // + self-loop
        OUT[node * D + j] = RELU ? fmaxf(o, 0.0f) : o;
    }
}

// ---------------- launch ----------------

extern "C" void kernel_launch(void* const* d_in, const int* in_sizes, int n_in,
                              void* d_out, int out_size, void* d_ws, size_t ws_size,
                              hipStream_t stream) {
    const float* row_embed = (const float*)d_in[0];
    const float* col_embed = (const float*)d_in[1];
    const float* W0 = (const float*)d_in[2];
    const float* b0 = (const float*)d_in[3];
    const float* W1 = (const float*)d_in[4];
    const float* b1 = (const float*)d_in[5];
    const float* W2 = (const float*)d_in[6];
    const float* b2 = (const float*)d_in[7];
    const int* ei = (const int*)d_in[8];
    const int* src = ei;
    const int* dst = ei + NEDGE;
    float* out = (float*)d_out;

    float* H = (float*)d_ws;
    float* B0 = H + (size_t)NNODES * D;
    unsigned int* binned = (unsigned int*)(B0 + (size_t)NNODES * D);
    int* binCnt = (int*)(binned + NEDGE);
    int* binPtr = binCnt + NBINS;
    int* binCursor = binPtr + (NBINS + 1);

    const dim3 blk(256);
    const int row_grid = (NNODES + 7) / 8;

    // bin build (every call — no cross-call state)
    zero_bins<<<(NBINS + 255) / 256, blk, 0, stream>>>(binCnt);
    bin_hist<<<B1_BLOCKS, blk, 0, stream>>>(dst, binCnt);
    bin_scan<<<1, 256, 0, stream>>>(binCnt, binPtr, binCursor);
    bin_scatter<<<B3_BLOCKS, blk, 0, stream>>>(src, dst, binCursor, binned);

    // layer 0
    linear_kernel<0><<<row_grid, blk, 0, stream>>>(row_embed, col_embed, W0, b0, H);
    agg_lds<false><<<NBINS, blk, 0, stream>>>(binPtr, binned, H, B0);
    // layer 1
    linear_kernel<1><<<row_grid, blk, 0, stream>>>(B0, nullptr, W1, b1, H);
    agg_lds<false><<<NBINS, blk, 0, stream>>>(binPtr, binned, H, B0);
    // layer 2 (fused output ReLU)
    linear_kernel<1><<<row_grid, blk, 0, stream>>>(B0, nullptr, W2, b2, H);
    agg_lds<true><<<NBINS, blk, 0, stream>>>(binPtr, binned, H, out);

    (void)in_sizes; (void)n_in; (void)out_size; (void)ws_size;
}

// Round 4
// 651.068 us; speedup vs baseline: 4.5761x; 4.5761x over previous
//
#include <hip/hip_runtime.h>

#define N_ROWS 100000
#define NNODES 150000
#define D 32
#define NEDGE 5000000
#define BINSHIFT 7
#define BINSZ 128                     // nodes per bin
#define NBINS 1172                    // ceil(150000 / 128)
#define B1_BLOCKS 1024
#define B3_BLOCKS 512

// ---------------- stage 1: coarse binning by dst>>7 (no divergent global atomics) ----------------

__global__ void zero_bins(int* __restrict__ binCnt) {
    int i = blockIdx.x * blockDim.x + threadIdx.x;
    if (i < NBINS) binCnt[i] = 0;
}

__global__ void bin_hist(const int* __restrict__ dst, int* __restrict__ binCnt) {
    __shared__ int h[NBINS];
    for (int b = threadIdx.x; b < NBINS; b += blockDim.x) h[b] = 0;
    __syncthreads();
    int i = blockIdx.x * blockDim.x + threadIdx.x;
    const int stride = gridDim.x * blockDim.x;
    for (; i < NEDGE; i += stride) atomicAdd(&h[dst[i] >> BINSHIFT], 1);
    __syncthreads();
    for (int b = threadIdx.x; b < NBINS; b += blockDim.x) {
        int c = h[b];
        if (c) atomicAdd(&binCnt[b], c);  // lane-consecutive: coalesced atomics
    }
}

__global__ void bin_scan(const int* __restrict__ binCnt, int* __restrict__ binPtr,
                         int* __restrict__ binCursor) {
    __shared__ int s[256];
    __shared__ int carry;
    const int t = threadIdx.x;
    if (t == 0) carry = 0;
    __syncthreads();
    for (int c = 0; c < (NBINS + 255) / 256; ++c) {
        int idx = c * 256 + t;
        int v = (idx < NBINS) ? binCnt[idx] : 0;
        s[t] = v;
        __syncthreads();
        for (int off = 1; off < 256; off <<= 1) {
            int tmp = (t >= off) ? s[t - off] : 0;
            __syncthreads();
            s[t] += tmp;
            __syncthreads();
        }
        int excl = carry + ((t == 0) ? 0 : s[t - 1]);
        if (idx < NBINS) { binPtr[idx] = excl; binCursor[idx] = excl; }
        __syncthreads();
        if (t == 0) carry += s[255];
        __syncthreads();
    }
    if (t == 0) binPtr[NBINS] = NEDGE;
}

// packed word: (dst & 127) << 18 | src   (src < 150000 < 2^18)
__global__ void bin_scatter(const int* __restrict__ src, const int* __restrict__ dst,
                            int* __restrict__ binCursor, unsigned int* __restrict__ binned) {
    __shared__ int h[NBINS];
    __shared__ int base[NBINS];
    const int t = threadIdx.x;
    for (int b = t; b < NBINS; b += 256) h[b] = 0;
    __syncthreads();
    const int chunk = (NEDGE + B3_BLOCKS - 1) / B3_BLOCKS;
    const int e0 = blockIdx.x * chunk;
    const int e1 = min(e0 + chunk, NEDGE);
    for (int i = e0 + t; i < e1; i += 256) atomicAdd(&h[dst[i] >> BINSHIFT], 1);
    __syncthreads();
    for (int b = t; b < NBINS; b += 256) {
        int c = h[b];
        base[b] = c ? atomicAdd(&binCursor[b], c) : 0;  // one reservation per (block,bin)
        h[b] = 0;
    }
    __syncthreads();
    for (int i = e0 + t; i < e1; i += 256) {
        int dv = dst[i];
        int bn = dv >> BINSHIFT;
        int r = atomicAdd(&h[bn], 1);  // LDS rank
        binned[base[bn] + r] = ((unsigned)(dv & (BINSZ - 1)) << 18) | (unsigned)src[i];
    }
}

// ---------------- stage 2: per-bin fine counting sort -> full CSR by dst ----------------

__global__ void fine_sort(const int* __restrict__ binPtr, const unsigned int* __restrict__ binned,
                          int* __restrict__ rowptr, int* __restrict__ srcSorted) {
    __shared__ int cnt[BINSZ];
    __shared__ int cur[BINSZ];
    const int t = threadIdx.x;
    const int bin = blockIdx.x;
    const int nodeBase = bin << BINSHIFT;
    const int nNodes = min(BINSZ, NNODES - nodeBase);
    const int e0 = binPtr[bin];
    const int e1 = binPtr[bin + 1];

    if (t < BINSZ) cnt[t] = 0;
    __syncthreads();
    for (int e = e0 + t; e < e1; e += 256) atomicAdd(&cnt[binned[e] >> 18], 1);
    __syncthreads();
    // exclusive scan of 128 counters (threads 0..127, Hillis-Steele)
    if (t < BINSZ) cur[t] = cnt[t];
    __syncthreads();
    for (int off = 1; off < BINSZ; off <<= 1) {
        int v = 0;
        if (t < BINSZ && t >= off) v = cur[t - off];
        __syncthreads();
        if (t < BINSZ) cur[t] += v;
        __syncthreads();
    }
    // cur[r] now inclusive; convert to exclusive start positions
    if (t < BINSZ) {
        int excl = cur[t] - cnt[t];
        if (t < nNodes) rowptr[nodeBase + t] = e0 + excl;
        cur[t] = excl;
    }
    __syncthreads();
    for (int e = e0 + t; e < e1; e += 256) {
        unsigned u = binned[e];
        int r = atomicAdd(&cur[u >> 18], 1);
        srcSorted[e0 + r] = (int)(u & 0x3FFFFu);
    }
    if (bin == 0 && t == 0) rowptr[NNODES] = NEDGE;
}

// ---------------- per-layer compute ----------------

// h[i][j] = sum_k act(x[i][k]) * W[j][k] + b[j]
template <int MODE>
__global__ void linear_kernel(const float* __restrict__ xa, const float* __restrict__ xb,
                              const float* __restrict__ W, const float* __restrict__ b,
                              float* __restrict__ H) {
    __shared__ float Wt[D * D];
    __shared__ float bs[D];
    const int tid = threadIdx.x;
    for (int t = tid; t < D * D; t += blockDim.x) {
        int j = t / D, k = t % D;
        Wt[k * D + j] = W[j * D + k];
    }
    if (tid < D) bs[tid] = b[tid];
    __syncthreads();

    const int row = blockIdx.x * (blockDim.x / D) + tid / D;
    const int j = tid % D;
    if (row >= NNODES) return;

    float xv;
    if (MODE == 0) {
        xv = (row < N_ROWS) ? xa[row * D + j] : xb[(row - N_ROWS) * D + j];
    } else {
        xv = fmaxf(xa[row * D + j], 0.0f);
    }

    float acc = bs[j];
#pragma unroll
    for (int k = 0; k < D; ++k) {
        float a = __shfl(xv, k, D);
        acc = fmaf(a, Wt[k * D + j], acc);
    }
    H[row * D + j] = acc;
}

// One 32-lane group per dst row: acc = H[d] (self-loop) + sum over CSR bucket.
// 18750 blocks / ~75K waves -> latency hidden by TLP.
template <bool RELU>
__global__ void agg_csr(const int* __restrict__ rowptr, const int* __restrict__ srcSorted,
                        const float* __restrict__ H, float* __restrict__ OUT) {
    const int tid = threadIdx.x;
    const int d = blockIdx.x * (blockDim.x >> 5) + (tid >> 5);
    const int j = tid & 31;
    if (d >= NNODES) return;

    int e = rowptr[d];
    const int eEnd = rowptr[d + 1];
    float acc = H[d * D + j];  // self-loop
    for (; e + 3 < eEnd; e += 4) {
        const int s0 = srcSorted[e];
        const int s1 = srcSorted[e + 1];
        const int s2 = srcSorted[e + 2];
        const int s3 = srcSorted[e + 3];
        const float v0 = H[s0 * D + j];
        const float v1 = H[s1 * D + j];
        const float v2 = H[s2 * D + j];
        const float v3 = H[s3 * D + j];
        acc += v0 + v1 + v2 + v3;
    }
    for (; e < eEnd; ++e) acc += H[srcSorted[e] * D + j];
    OUT[d * D + j] = RELU ? fmaxf(acc, 0.0f) : acc;
}

// ---------------- launch ----------------

extern "C" void kernel_launch(void* const* d_in, const int* in_sizes, int n_in,
                              void* d_out, int out_size, void* d_ws, size_t ws_size,
                              hipStream_t stream) {
    const float* row_embed = (const float*)d_in[0];
    const float* col_embed = (const float*)d_in[1];
    const float* W0 = (const float*)d_in[2];
    const float* b0 = (const float*)d_in[3];
    const float* W1 = (const float*)d_in[4];
    const float* b1 = (const float*)d_in[5];
    const float* W2 = (const float*)d_in[6];
    const float* b2 = (const float*)d_in[7];
    const int* ei = (const int*)d_in[8];
    const int* src = ei;
    const int* dst = ei + NEDGE;
    float* out = (float*)d_out;

    // workspace carve-up (4-byte elements); total ~79 MB
    float* H = (float*)d_ws;
    float* B0 = H + (size_t)NNODES * D;
    unsigned int* binned = (unsigned int*)(B0 + (size_t)NNODES * D);
    int* srcSorted = (int*)(binned + NEDGE);
    int* binCnt = srcSorted + NEDGE;
    int* binPtr = binCnt + NBINS;
    int* binCursor = binPtr + (NBINS + 1);
    int* rowptr = binCursor + NBINS;

    const dim3 blk(256);
    const int row_grid = (NNODES + 7) / 8;

    // CSR build (every call — no cross-call state)
    zero_bins<<<(NBINS + 255) / 256, blk, 0, stream>>>(binCnt);
    bin_hist<<<B1_BLOCKS, blk, 0, stream>>>(dst, binCnt);
    bin_scan<<<1, 256, 0, stream>>>(binCnt, binPtr, binCursor);
    bin_scatter<<<B3_BLOCKS, blk, 0, stream>>>(src, dst, binCursor, binned);
    fine_sort<<<NBINS, blk, 0, stream>>>(binPtr, binned, rowptr, srcSorted);

    // layer 0
    linear_kernel<0><<<row_grid, blk, 0, stream>>>(row_embed, col_embed, W0, b0, H);
    agg_csr<false><<<row_grid, blk, 0, stream>>>(rowptr, srcSorted, H, B0);
    // layer 1
    linear_kernel<1><<<row_grid, blk, 0, stream>>>(B0, nullptr, W1, b1, H);
    agg_csr<false><<<row_grid, blk, 0, stream>>>(rowptr, srcSorted, H, B0);
    // layer 2 (fused output ReLU)
    linear_kernel<1><<<row_grid, blk, 0, stream>>>(B0, nullptr, W2, b2, H);
    agg_csr<true><<<row_grid, blk, 0, stream>>>(rowptr, srcSorted, H, out);

    (void)in_sizes; (void)n_in; (void)out_size; (void)ws_size;
}

// Round 5
// 599.319 us; speedup vs baseline: 4.9712x; 1.0863x over previous
//
#include <hip/hip_runtime.h>
#include <hip/hip_fp16.h>

#define N_ROWS 100000
#define NNODES 150000
#define D 32
#define NEDGE 5000000
#define BINSHIFT 7
#define BINSZ 128                          // nodes per bin
#define NBINS 1172                         // ceil(150000 / 128)
#define NBLK 512                           // scatter blocks
#define CPB ((NEDGE + NBLK - 1) / NBLK)    // 9766 edges per block
#define NCOUNTS (NBINS * NBLK)             // 600064
#define SCAN_ITEMS 1024
#define NSCAN (NCOUNTS / SCAN_ITEMS)       // 586 (exact)

// ---------------- stage 1: per-(block,bin) counts matrix (no atomics) ----------------

__global__ void count_kernel(const int* __restrict__ dst, int* __restrict__ counts) {
    __shared__ int h[NBINS];
    const int t = threadIdx.x;
    for (int b = t; b < NBINS; b += 256) h[b] = 0;
    __syncthreads();
    const int e0 = blockIdx.x * CPB;
    const int e1 = min(e0 + CPB, NEDGE);
    for (int i = e0 + t; i < e1; i += 256) atomicAdd(&h[dst[i] >> BINSHIFT], 1);
    __syncthreads();
    for (int b = t; b < NBINS; b += 256) counts[b * NBLK + blockIdx.x] = h[b];
}

// ---------------- stage 2: device-wide exclusive scan of counts (600064 ints) ----------------

__global__ void scanA(const int* __restrict__ counts, int* __restrict__ partials) {
    __shared__ int s[256];
    const int t = threadIdx.x;
    const int base = blockIdx.x * SCAN_ITEMS + t * 4;
    int sum = 0;
#pragma unroll
    for (int k = 0; k < 4; ++k) sum += counts[base + k];
    s[t] = sum;
    __syncthreads();
    for (int off = 128; off > 0; off >>= 1) {
        if (t < off) s[t] += s[t + off];
        __syncthreads();
    }
    if (t == 0) partials[blockIdx.x] = s[0];
}

__global__ void scanB(int* __restrict__ partials) {
    __shared__ int s[256];
    __shared__ int carry;
    const int t = threadIdx.x;
    if (t == 0) carry = 0;
    __syncthreads();
    for (int c = 0; c < (NSCAN + 255) / 256; ++c) {
        int idx = c * 256 + t;
        int v = (idx < NSCAN) ? partials[idx] : 0;
        s[t] = v;
        __syncthreads();
        for (int off = 1; off < 256; off <<= 1) {
            int tmp = (t >= off) ? s[t - off] : 0;
            __syncthreads();
            s[t] += tmp;
            __syncthreads();
        }
        if (idx < NSCAN) partials[idx] = carry + s[t] - v;  // exclusive
        __syncthreads();
        if (t == 0) carry += s[255];
        __syncthreads();
    }
}

__global__ void scanC(const int* __restrict__ counts, const int* __restrict__ partials,
                      int* __restrict__ bases, int* __restrict__ binPtr) {
    __shared__ int s[256];
    const int t = threadIdx.x;
    const int base = blockIdx.x * SCAN_ITEMS + t * 4;
    int c[4];
    int sum = 0;
#pragma unroll
    for (int k = 0; k < 4; ++k) { c[k] = counts[base + k]; sum += c[k]; }
    s[t] = sum;
    __syncthreads();
    for (int off = 1; off < 256; off <<= 1) {
        int v = (t >= off) ? s[t - off] : 0;
        __syncthreads();
        s[t] += v;
        __syncthreads();
    }
    int run = partials[blockIdx.x] + ((t == 0) ? 0 : s[t - 1]);
#pragma unroll
    for (int k = 0; k < 4; ++k) {
        int idx = base + k;
        bases[idx] = run;
        if ((idx & (NBLK - 1)) == 0) binPtr[idx / NBLK] = run;  // NBLK = 512 (pow2)
        run += c[k];
    }
    if (blockIdx.x == 0 && t == 0) binPtr[NBINS] = NEDGE;
}

// ---------------- stage 3: deterministic scatter (packed (dstLocal<<18)|src) ----------------

__global__ void scatter2(const int* __restrict__ src, const int* __restrict__ dst,
                         const int* __restrict__ bases, unsigned int* __restrict__ binned) {
    __shared__ int h[NBINS];
    __shared__ int base[NBINS];
    const int t = threadIdx.x;
    for (int b = t; b < NBINS; b += 256) {
        h[b] = 0;
        base[b] = bases[b * NBLK + blockIdx.x];
    }
    __syncthreads();
    const int e0 = blockIdx.x * CPB;
    const int e1 = min(e0 + CPB, NEDGE);
    for (int i = e0 + t; i < e1; i += 256) {
        int dv = dst[i];
        int bn = dv >> BINSHIFT;
        int r = atomicAdd(&h[bn], 1);  // LDS rank only — no global atomics
        binned[base[bn] + r] = ((unsigned)(dv & (BINSZ - 1)) << 18) | (unsigned)src[i];
    }
}

// ---------------- stage 4: per-bin fine counting sort -> full CSR by dst ----------------

__global__ void fine_sort(const int* __restrict__ binPtr, const unsigned int* __restrict__ binned,
                          int* __restrict__ rowptr, int* __restrict__ srcSorted) {
    __shared__ int cnt[BINSZ];
    __shared__ int cur[BINSZ];
    const int t = threadIdx.x;
    const int bin = blockIdx.x;
    const int nodeBase = bin << BINSHIFT;
    const int nNodes = min(BINSZ, NNODES - nodeBase);
    const int e0 = binPtr[bin];
    const int e1 = binPtr[bin + 1];

    if (t < BINSZ) cnt[t] = 0;
    __syncthreads();
    for (int e = e0 + t; e < e1; e += 256) atomicAdd(&cnt[binned[e] >> 18], 1);
    __syncthreads();
    if (t < BINSZ) cur[t] = cnt[t];
    __syncthreads();
    for (int off = 1; off < BINSZ; off <<= 1) {
        int v = 0;
        if (t < BINSZ && t >= off) v = cur[t - off];
        __syncthreads();
        if (t < BINSZ) cur[t] += v;
        __syncthreads();
    }
    if (t < BINSZ) {
        int excl = cur[t] - cnt[t];
        if (t < nNodes) rowptr[nodeBase + t] = e0 + excl;
        cur[t] = excl;
    }
    __syncthreads();
    for (int e = e0 + t; e < e1; e += 256) {
        unsigned u = binned[e];
        int r = atomicAdd(&cur[u >> 18], 1);
        srcSorted[e0 + r] = (int)(u & 0x3FFFFu);
    }
    if (bin == 0 && t == 0) rowptr[NNODES] = NEDGE;
}

// ---------------- per-layer compute ----------------

// h[i][j] = sum_k act(x[i][k]) * W[j][k] + b[j]; H stored fp16 (halves gather lines in agg)
template <int MODE>
__global__ void linear_kernel(const float* __restrict__ xa, const float* __restrict__ xb,
                              const float* __restrict__ W, const float* __restrict__ b,
                              __half* __restrict__ H) {
    __shared__ float Wt[D * D];
    __shared__ float bs[D];
    const int tid = threadIdx.x;
    for (int t = tid; t < D * D; t += blockDim.x) {
        int j = t / D, k = t % D;
        Wt[k * D + j] = W[j * D + k];
    }
    if (tid < D) bs[tid] = b[tid];
    __syncthreads();

    const int row = blockIdx.x * (blockDim.x / D) + tid / D;
    const int j = tid % D;
    if (row >= NNODES) return;

    float xv;
    if (MODE == 0) {
        xv = (row < N_ROWS) ? xa[row * D + j] : xb[(row - N_ROWS) * D + j];
    } else {
        xv = fmaxf(xa[row * D + j], 0.0f);
    }

    float acc = bs[j];
#pragma unroll
    for (int k = 0; k < D; ++k) {
        float a = __shfl(xv, k, D);
        acc = fmaf(a, Wt[k * D + j], acc);
    }
    H[row * D + j] = __float2half(acc);
}

// One 32-lane group per dst row; fp16 gathers, f32 accumulate.
template <bool RELU>
__global__ void agg_csr(const int* __restrict__ rowptr, const int* __restrict__ srcSorted,
                        const __half* __restrict__ H, float* __restrict__ OUT) {
    const int tid = threadIdx.x;
    const int d = blockIdx.x * (blockDim.x >> 5) + (tid >> 5);
    const int j = tid & 31;
    if (d >= NNODES) return;

    int e = rowptr[d];
    const int eEnd = rowptr[d + 1];
    float acc = __half2float(H[d * D + j]);  // self-loop
    for (; e + 3 < eEnd; e += 4) {
        const int s0 = srcSorted[e];
        const int s1 = srcSorted[e + 1];
        const int s2 = srcSorted[e + 2];
        const int s3 = srcSorted[e + 3];
        const float v0 = __half2float(H[s0 * D + j]);
        const float v1 = __half2float(H[s1 * D + j]);
        const float v2 = __half2float(H[s2 * D + j]);
        const float v3 = __half2float(H[s3 * D + j]);
        acc += v0 + v1 + v2 + v3;
    }
    for (; e < eEnd; ++e) acc += __half2float(H[srcSorted[e] * D + j]);
    OUT[d * D + j] = RELU ? fmaxf(acc, 0.0f) : acc;
}

// ---------------- launch ----------------

extern "C" void kernel_launch(void* const* d_in, const int* in_sizes, int n_in,
                              void* d_out, int out_size, void* d_ws, size_t ws_size,
                              hipStream_t stream) {
    const float* row_embed = (const float*)d_in[0];
    const float* col_embed = (const float*)d_in[1];
    const float* W0 = (const float*)d_in[2];
    const float* b0 = (const float*)d_in[3];
    const float* W1 = (const float*)d_in[4];
    const float* b1 = (const float*)d_in[5];
    const float* W2 = (const float*)d_in[6];
    const float* b2 = (const float*)d_in[7];
    const int* ei = (const int*)d_in[8];
    const int* src = ei;
    const int* dst = ei + NEDGE;
    float* out = (float*)d_out;

    // workspace carve-up (~74 MB)
    __half* H = (__half*)d_ws;                                  // 9.6 MB
    float* B0 = (float*)(H + (size_t)NNODES * D);               // 19.2 MB
    unsigned int* binned = (unsigned int*)(B0 + (size_t)NNODES * D);  // 20 MB
    int* srcSorted = (int*)(binned + NEDGE);                    // 20 MB
    int* counts = srcSorted + NEDGE;                            // 2.4 MB
    int* bases = counts + NCOUNTS;                              // 2.4 MB
    int* partials = bases + NCOUNTS;                            // 586
    int* binPtr = partials + NSCAN;                             // NBINS+1
    int* rowptr = binPtr + (NBINS + 1);                         // NNODES+1

    const dim3 blk(256);
    const int row_grid = (NNODES + 7) / 8;

    // CSR build — atomic-free counting sort (rebuilt every call; stateless)
    count_kernel<<<NBLK, blk, 0, stream>>>(dst, counts);
    scanA<<<NSCAN, blk, 0, stream>>>(counts, partials);
    scanB<<<1, 256, 0, stream>>>(partials);
    scanC<<<NSCAN, blk, 0, stream>>>(counts, partials, bases, binPtr);
    scatter2<<<NBLK, blk, 0, stream>>>(src, dst, bases, binned);
    fine_sort<<<NBINS, blk, 0, stream>>>(binPtr, binned, rowptr, srcSorted);

    // layer 0
    linear_kernel<0><<<row_grid, blk, 0, stream>>>(row_embed, col_embed, W0, b0, H);
    agg_csr<false><<<row_grid, blk, 0, stream>>>(rowptr, srcSorted, H, B0);
    // layer 1
    linear_kernel<1><<<row_grid, blk, 0, stream>>>(B0, nullptr, W1, b1, H);
    agg_csr<false><<<row_grid, blk, 0, stream>>>(rowptr, srcSorted, H, B0);
    // layer 2 (fused output ReLU)
    linear_kernel<1><<<row_grid, blk, 0, stream>>>(B0, nullptr, W2, b2, H);
    agg_csr<true><<<row_grid, blk, 0, stream>>>(rowptr, srcSorted, H, out);

    (void)in_sizes; (void)n_in; (void)out_size; (void)ws_size;
}

// Round 6
// 498.877 us; speedup vs baseline: 5.9721x; 1.2013x over previous
//
#include <hip/hip_runtime.h>
#include <hip/hip_fp16.h>

#define N_ROWS 100000
#define NNODES 150000
#define D 32
#define NEDGE 5000000
#define BINSHIFT 7
#define BINSZ 128                          // nodes per bin
#define NBINS 1172                         // ceil(150000 / 128)
#define NBLK 512                           // scatter/count blocks
#define SCT 1024                           // threads per scatter/count block (16 waves)
#define CPB ((NEDGE + NBLK - 1) / NBLK)    // 9766 edges per block
#define NCOUNTS (NBINS * NBLK)             // 600064
#define SCAN_ITEMS 1024
#define NSCAN (NCOUNTS / SCAN_ITEMS)       // 586 (exact)

// ---------------- stage 1: per-(block,bin) counts matrix (no global atomics) ----------------

__global__ void count_kernel(const int* __restrict__ dst, int* __restrict__ counts) {
    __shared__ int h[NBINS];
    const int t = threadIdx.x;
    for (int b = t; b < NBINS; b += SCT) h[b] = 0;
    __syncthreads();
    const int e0 = blockIdx.x * CPB;
    const int e1 = min(e0 + CPB, NEDGE);
    for (int i = e0 + t; i < e1; i += SCT) atomicAdd(&h[dst[i] >> BINSHIFT], 1);
    __syncthreads();
    for (int b = t; b < NBINS; b += SCT) counts[b * NBLK + blockIdx.x] = h[b];
}

// ---------------- stage 2: device-wide exclusive scan of counts (600064 ints) ----------------

__global__ void scanA(const int* __restrict__ counts, int* __restrict__ partials) {
    __shared__ int s[256];
    const int t = threadIdx.x;
    const int base = blockIdx.x * SCAN_ITEMS + t * 4;
    int sum = 0;
#pragma unroll
    for (int k = 0; k < 4; ++k) sum += counts[base + k];
    s[t] = sum;
    __syncthreads();
    for (int off = 128; off > 0; off >>= 1) {
        if (t < off) s[t] += s[t + off];
        __syncthreads();
    }
    if (t == 0) partials[blockIdx.x] = s[0];
}

__global__ void scanB(int* __restrict__ partials) {
    __shared__ int s[256];
    __shared__ int carry;
    const int t = threadIdx.x;
    if (t == 0) carry = 0;
    __syncthreads();
    for (int c = 0; c < (NSCAN + 255) / 256; ++c) {
        int idx = c * 256 + t;
        int v = (idx < NSCAN) ? partials[idx] : 0;
        s[t] = v;
        __syncthreads();
        for (int off = 1; off < 256; off <<= 1) {
            int tmp = (t >= off) ? s[t - off] : 0;
            __syncthreads();
            s[t] += tmp;
            __syncthreads();
        }
        if (idx < NSCAN) partials[idx] = carry + s[t] - v;  // exclusive
        __syncthreads();
        if (t == 0) carry += s[255];
        __syncthreads();
    }
}

__global__ void scanC(const int* __restrict__ counts, const int* __restrict__ partials,
                      int* __restrict__ bases, int* __restrict__ binPtr) {
    __shared__ int s[256];
    const int t = threadIdx.x;
    const int base = blockIdx.x * SCAN_ITEMS + t * 4;
    int c[4];
    int sum = 0;
#pragma unroll
    for (int k = 0; k < 4; ++k) { c[k] = counts[base + k]; sum += c[k]; }
    s[t] = sum;
    __syncthreads();
    for (int off = 1; off < 256; off <<= 1) {
        int v = (t >= off) ? s[t - off] : 0;
        __syncthreads();
        s[t] += v;
        __syncthreads();
    }
    int run = partials[blockIdx.x] + ((t == 0) ? 0 : s[t - 1]);
#pragma unroll
    for (int k = 0; k < 4; ++k) {
        int idx = base + k;
        bases[idx] = run;
        if ((idx & (NBLK - 1)) == 0) binPtr[idx / NBLK] = run;  // NBLK pow2
        run += c[k];
    }
    if (blockIdx.x == 0 && t == 0) binPtr[NBINS] = NEDGE;
}

// ---------------- stage 3: deterministic scatter (packed (dstLocal<<18)|src) ----------------

__global__ void scatter2(const int* __restrict__ src, const int* __restrict__ dst,
                         const int* __restrict__ bases, unsigned int* __restrict__ binned) {
    __shared__ int h[NBINS];
    __shared__ int base[NBINS];
    const int t = threadIdx.x;
    for (int b = t; b < NBINS; b += SCT) {
        h[b] = 0;
        base[b] = bases[b * NBLK + blockIdx.x];
    }
    __syncthreads();
    const int e0 = blockIdx.x * CPB;
    const int e1 = min(e0 + CPB, NEDGE);
    for (int i = e0 + t; i < e1; i += SCT) {
        int dv = dst[i];
        int bn = dv >> BINSHIFT;
        int r = atomicAdd(&h[bn], 1);  // LDS rank only
        binned[base[bn] + r] = ((unsigned)(dv & (BINSZ - 1)) << 18) | (unsigned)src[i];
    }
}

// ---------------- stage 4: per-bin fine counting sort -> full CSR by dst ----------------

__global__ void fine_sort(const int* __restrict__ binPtr, const unsigned int* __restrict__ binned,
                          int* __restrict__ rowptr, int* __restrict__ srcSorted) {
    __shared__ int cnt[BINSZ];
    __shared__ int cur[BINSZ];
    const int t = threadIdx.x;  // 512 threads
    const int bin = blockIdx.x;
    const int nodeBase = bin << BINSHIFT;
    const int nNodes = min(BINSZ, NNODES - nodeBase);
    const int e0 = binPtr[bin];
    const int e1 = binPtr[bin + 1];

    if (t < BINSZ) cnt[t] = 0;
    __syncthreads();
    for (int e = e0 + t; e < e1; e += 512) atomicAdd(&cnt[binned[e] >> 18], 1);
    __syncthreads();
    if (t < BINSZ) cur[t] = cnt[t];
    __syncthreads();
    for (int off = 1; off < BINSZ; off <<= 1) {
        int v = 0;
        if (t < BINSZ && t >= off) v = cur[t - off];
        __syncthreads();
        if (t < BINSZ) cur[t] += v;
        __syncthreads();
    }
    if (t < BINSZ) {
        int excl = cur[t] - cnt[t];
        if (t < nNodes) rowptr[nodeBase + t] = e0 + excl;
        cur[t] = excl;
    }
    __syncthreads();
    for (int e = e0 + t; e < e1; e += 512) {
        unsigned u = binned[e];
        int r = atomicAdd(&cur[u >> 18], 1);
        srcSorted[e0 + r] = (int)(u & 0x3FFFFu);
    }
    if (bin == 0 && t == 0) rowptr[NNODES] = NEDGE;
}

// ---------------- layer 0 linear: embeddings -> H0 (fp16) ----------------

__global__ void linear0(const float* __restrict__ xa, const float* __restrict__ xb,
                        const float* __restrict__ W, const float* __restrict__ b,
                        __half* __restrict__ H) {
    __shared__ float Wt[D * D];
    __shared__ float bs[D];
    const int tid = threadIdx.x;
    for (int t = tid; t < D * D; t += blockDim.x) {
        int j = t / D, k = t % D;
        Wt[k * D + j] = W[j * D + k];
    }
    if (tid < D) bs[tid] = b[tid];
    __syncthreads();

    const int row = blockIdx.x * 8 + (tid >> 5);
    const int j = tid & 31;

    float xv = (row < N_ROWS) ? xa[row * D + j] : xb[(row - N_ROWS) * D + j];

    float acc = bs[j];
#pragma unroll
    for (int k = 0; k < D; ++k) {
        float a = __shfl(xv, k, D);
        acc = fmaf(a, Wt[k * D + j], acc);
    }
    H[row * D + j] = __float2half(acc);
}

// ---------------- fused aggregate (+ReLU) (+next linear) ----------------
// acc = Hin[d] + sum_{e in CSR[d]} Hin[src[e]];  x = relu(acc)
// LAST:  out[d] = x (f32)
// !LAST: Hout[d] = fp16( b + x . W^T )  via shfl-broadcast FMA
template <bool LAST>
__global__ void agg_fused(const int* __restrict__ rowptr, const int* __restrict__ srcSorted,
                          const __half* __restrict__ Hin, const float* __restrict__ W,
                          const float* __restrict__ b, __half* __restrict__ Hout,
                          float* __restrict__ out) {
    __shared__ float Wt[D * D];
    __shared__ float bs[D];
    const int tid = threadIdx.x;
    if (!LAST) {
        for (int t = tid; t < D * D; t += 256) {
            int j = t / D, k = t % D;
            Wt[k * D + j] = W[j * D + k];
        }
        if (tid < D) bs[tid] = b[tid];
        __syncthreads();
    }

    const int d = blockIdx.x * 8 + (tid >> 5);  // NNODES % 8 == 0: no partial block
    const int j = tid & 31;

    int e = rowptr[d];
    const int eEnd = rowptr[d + 1];
    float acc = __half2float(Hin[d * D + j]);  // self-loop
    for (; e + 3 < eEnd; e += 4) {
        const int s0 = srcSorted[e];
        const int s1 = srcSorted[e + 1];
        const int s2 = srcSorted[e + 2];
        const int s3 = srcSorted[e + 3];
        const float v0 = __half2float(Hin[s0 * D + j]);
        const float v1 = __half2float(Hin[s1 * D + j]);
        const float v2 = __half2float(Hin[s2 * D + j]);
        const float v3 = __half2float(Hin[s3 * D + j]);
        acc += v0 + v1 + v2 + v3;
    }
    for (; e < eEnd; ++e) acc += __half2float(Hin[srcSorted[e] * D + j]);

    const float xv = fmaxf(acc, 0.0f);
    if (LAST) {
        out[d * D + j] = xv;
    } else {
        float nacc = bs[j];
#pragma unroll
        for (int k = 0; k < D; ++k) {
            float a = __shfl(xv, k, D);
            nacc = fmaf(a, Wt[k * D + j], nacc);
        }
        Hout[d * D + j] = __float2half(nacc);
    }
}

// ---------------- launch ----------------

extern "C" void kernel_launch(void* const* d_in, const int* in_sizes, int n_in,
                              void* d_out, int out_size, void* d_ws, size_t ws_size,
                              hipStream_t stream) {
    const float* row_embed = (const float*)d_in[0];
    const float* col_embed = (const float*)d_in[1];
    const float* W0 = (const float*)d_in[2];
    const float* b0 = (const float*)d_in[3];
    const float* W1 = (const float*)d_in[4];
    const float* b1 = (const float*)d_in[5];
    const float* W2 = (const float*)d_in[6];
    const float* b2 = (const float*)d_in[7];
    const int* ei = (const int*)d_in[8];
    const int* src = ei;
    const int* dst = ei + NEDGE;
    float* out = (float*)d_out;

    // workspace carve-up (~64 MB)
    __half* H0 = (__half*)d_ws;                                  // 9.6 MB
    __half* H1 = H0 + (size_t)NNODES * D;                        // 9.6 MB
    unsigned int* binned = (unsigned int*)(H1 + (size_t)NNODES * D);  // 20 MB
    int* srcSorted = (int*)(binned + NEDGE);                     // 20 MB
    int* counts = srcSorted + NEDGE;                             // 2.4 MB
    int* bases = counts + NCOUNTS;                               // 2.4 MB
    int* partials = bases + NCOUNTS;                             // 586
    int* binPtr = partials + NSCAN;                              // NBINS+1
    int* rowptr = binPtr + (NBINS + 1);                          // NNODES+1

    const int row_grid = NNODES / 8;  // 18750 exact

    // CSR build — atomic-free counting sort (rebuilt every call; stateless)
    count_kernel<<<NBLK, SCT, 0, stream>>>(dst, counts);
    scanA<<<NSCAN, 256, 0, stream>>>(counts, partials);
    scanB<<<1, 256, 0, stream>>>(partials);
    scanC<<<NSCAN, 256, 0, stream>>>(counts, partials, bases, binPtr);
    scatter2<<<NBLK, SCT, 0, stream>>>(src, dst, bases, binned);
    fine_sort<<<NBINS, 512, 0, stream>>>(binPtr, binned, rowptr, srcSorted);

    // layer 0 linear, then fused agg+linear chain
    linear0<<<row_grid, 256, 0, stream>>>(row_embed, col_embed, W0, b0, H0);
    agg_fused<false><<<row_grid, 256, 0, stream>>>(rowptr, srcSorted, H0, W1, b1, H1, nullptr);
    agg_fused<false><<<row_grid, 256, 0, stream>>>(rowptr, srcSorted, H1, W2, b2, H0, nullptr);
    agg_fused<true><<<row_grid, 256, 0, stream>>>(rowptr, srcSorted, H0, nullptr, nullptr, nullptr, out);

    (void)in_sizes; (void)n_in; (void)out_size; (void)ws_size;
}